// Round 5
// baseline (979.983 us; speedup 1.0000x reference)
//
#include <hip/hip_runtime.h>
#include <hip/hip_bf16.h>

// R-GCN (2-layer) + mean-pool + linear + softmax for MI355X.
// Counting-sort edges by relation (64-aligned buckets, padding -> dummy row N)
// so each wave handles a single-relation 64-edge chunk with W[r] column in
// VGPRs. Per edge: wave-uniform row loads (scalarizable -> s_load_dwordx16,
// broadcast) + v_fmac; coalesced 256B atomic scatter to agg[dst]. Finalize
// kernels fuse self-loop + bias + relu (+ run-length-batched mean-pool).

#define IN_DIM 32
#define HID 64
#define NREL 16
#define NCLS 8

__device__ __forceinline__ int rfl(int v) { return __builtin_amdgcn_readfirstlane(v); }

// ---------------- counting sort by relation ----------------

__global__ void hist_rel(const int* __restrict__ rel, int* __restrict__ hist, int E) {
  __shared__ int lh[NREL];
  int tid = threadIdx.x;
  if (tid < NREL) lh[tid] = 0;
  __syncthreads();
  for (int e = blockIdx.x * blockDim.x + tid; e < E; e += gridDim.x * blockDim.x)
    atomicAdd(&lh[rel[e]], 1);
  __syncthreads();
  if (tid < NREL && lh[tid] > 0) atomicAdd(&hist[tid], lh[tid]);
}

__global__ void scan16(const int* __restrict__ hist, int* __restrict__ offs,
                       int* __restrict__ fill) {
  if (threadIdx.x == 0) {
    int o = 0;
    for (int r = 0; r < NREL; ++r) {
      offs[r] = o;
      fill[r] = o;
      o += (hist[r] + 63) & ~63;   // 64-aligned buckets -> chunk has uniform rel
    }
    offs[NREL] = o;
  }
}

// padding entries: src=0 (safe row), dst=N (dummy agg row) -> branch-free edge loop
__global__ void fill_pad(int* __restrict__ ssrc, int* __restrict__ sdst, int Epad, int N) {
  int i = blockIdx.x * blockDim.x + threadIdx.x;
  if (i < Epad) { ssrc[i] = 0; sdst[i] = N; }
}

__global__ void scatter_rel(const int* __restrict__ rel, const int* __restrict__ src,
                            const int* __restrict__ dst, int* __restrict__ fill,
                            int* __restrict__ ssrc, int* __restrict__ sdst, int E) {
  __shared__ int lc[NREL];
  __shared__ int lbase[NREL];
  int tid = threadIdx.x;
  if (tid < NREL) lc[tid] = 0;
  __syncthreads();
  int e = blockIdx.x * blockDim.x + tid;
  int r = 0, lo = 0;
  bool valid = (e < E);
  if (valid) {
    r = rel[e];
    lo = atomicAdd(&lc[r], 1);
  }
  __syncthreads();
  if (tid < NREL && lc[tid] > 0) lbase[tid] = atomicAdd(&fill[tid], lc[tid]);
  __syncthreads();
  if (valid) {
    int p = lbase[r] + lo;
    ssrc[p] = src[e];
    sdst[p] = dst[e];
  }
}

// ---------------- per-edge transform + scatter-add ----------------
// One wave per 64-edge single-relation chunk. lane = output feature.
// Row address is wave-uniform (readlane -> SGPR) so the row load scalarizes
// (s_load_dwordx16) or collapses to a single broadcast transaction.

template <int IN>
__global__ void edge_layer(const float* __restrict__ hin,
                           const int* __restrict__ ssrc,
                           const int* __restrict__ sdst,
                           const float* __restrict__ W,
                           const int* __restrict__ offs,
                           float* __restrict__ agg,
                           int maxchunks) {
  const int lane = threadIdx.x & 63;
  int wid = rfl((int)(blockIdx.x * (blockDim.x >> 6) + (threadIdx.x >> 6)));
  if (wid >= maxchunks) return;
  const int base = wid * 64;

  int r = 0;
#pragma unroll
  for (int k = 1; k < NREL; ++k) r += (base >= offs[k]) ? 1 : 0;

  const float* Wr = W + (size_t)r * (IN * HID);
  float w[IN];
#pragma unroll
  for (int i = 0; i < IN; ++i) w[i] = Wr[i * HID + lane];

  const int myd = sdst[base + lane];   // per-lane coalesced, broadcast below
  const int mys = ssrc[base + lane];

#pragma unroll 4
  for (int k = 0; k < 64; ++k) {
    const int d = __builtin_amdgcn_readlane(myd, k);   // SGPR, wave-uniform
    const int s = __builtin_amdgcn_readlane(mys, k);
    const float4* __restrict__ row = (const float4*)(hin + (size_t)s * IN);
    float a0 = 0.f, a1 = 0.f, a2 = 0.f, a3 = 0.f;
#pragma unroll
    for (int i = 0; i < IN / 4; ++i) {
      float4 hv = row[i];              // uniform addr -> broadcast
      a0 = fmaf(hv.x, w[4 * i + 0], a0);
      a1 = fmaf(hv.y, w[4 * i + 1], a1);
      a2 = fmaf(hv.z, w[4 * i + 2], a2);
      a3 = fmaf(hv.w, w[4 * i + 3], a3);
    }
    atomicAdd(&agg[(size_t)d * HID + lane], (a0 + a1) + (a2 + a3));
  }
}

// ---------------- finalize: self-loop + bias + relu ----------------

__global__ void finalize1(const float* __restrict__ agg, const float* __restrict__ h,
                          const float* __restrict__ Wl, const float* __restrict__ b,
                          float* __restrict__ h1, int N) {
  const int lane = threadIdx.x & 63;
  int wid = rfl((int)(blockIdx.x * (blockDim.x >> 6) + (threadIdx.x >> 6)));
  int nw = gridDim.x * (blockDim.x >> 6);
  float wl[IN_DIM];
#pragma unroll
  for (int i = 0; i < IN_DIM; ++i) wl[i] = Wl[i * HID + lane];
  float bv = b[lane];
  for (int n = wid; n < N; n += nw) {
    const float4* __restrict__ row = (const float4*)(h + (size_t)n * IN_DIM);
    float a0 = 0.f, a1 = 0.f, a2 = 0.f, a3 = 0.f;
#pragma unroll
    for (int i = 0; i < IN_DIM / 4; ++i) {
      float4 hv = row[i];
      a0 = fmaf(hv.x, wl[4 * i + 0], a0);
      a1 = fmaf(hv.y, wl[4 * i + 1], a1);
      a2 = fmaf(hv.z, wl[4 * i + 2], a2);
      a3 = fmaf(hv.w, wl[4 * i + 3], a3);
    }
    float v = agg[(size_t)n * HID + lane] + (a0 + a1) + (a2 + a3) + bv;
    h1[(size_t)n * HID + lane] = fmaxf(v, 0.f);
  }
}

// finalize layer2 + fused mean-pool scatter (node2graph sorted -> run-length
// batch the atomics: ~1 flush per graph-change instead of per node)
__global__ void finalize2_pool(const float* __restrict__ agg, const float* __restrict__ h1,
                               const float* __restrict__ Wl, const float* __restrict__ b,
                               const int* __restrict__ n2g,
                               float* __restrict__ pooled, float* __restrict__ cnt, int N) {
  const int lane = threadIdx.x & 63;
  int wid = rfl((int)(blockIdx.x * (blockDim.x >> 6) + (threadIdx.x >> 6)));
  int nw = gridDim.x * (blockDim.x >> 6);
  int per = (N + nw - 1) / nw;
  int n0 = wid * per;
  int n1 = min(N, n0 + per);
  if (n0 >= n1) return;

  float wl[HID];
#pragma unroll
  for (int i = 0; i < HID; ++i) wl[i] = Wl[i * HID + lane];
  float bv = b[lane];

  float psum = 0.f, pcnt = 0.f;
  int pg = -1;
  for (int n = n0; n < n1; ++n) {
    const float4* __restrict__ row = (const float4*)(h1 + (size_t)n * HID);
    float a0 = 0.f, a1 = 0.f, a2 = 0.f, a3 = 0.f;
#pragma unroll
    for (int i = 0; i < HID / 4; ++i) {
      float4 hv = row[i];
      a0 = fmaf(hv.x, wl[4 * i + 0], a0);
      a1 = fmaf(hv.y, wl[4 * i + 1], a1);
      a2 = fmaf(hv.z, wl[4 * i + 2], a2);
      a3 = fmaf(hv.w, wl[4 * i + 3], a3);
    }
    float v = agg[(size_t)n * HID + lane] + (a0 + a1) + (a2 + a3) + bv;
    v = fmaxf(v, 0.f);
    int g = rfl(n2g[n]);
    if (g != pg) {
      if (pg >= 0) {
        atomicAdd(&pooled[(size_t)pg * HID + lane], psum);
        if (lane == 0) atomicAdd(&cnt[pg], pcnt);
      }
      pg = g; psum = 0.f; pcnt = 0.f;
    }
    psum += v; pcnt += 1.f;
  }
  if (pg >= 0) {
    atomicAdd(&pooled[(size_t)pg * HID + lane], psum);
    if (lane == 0) atomicAdd(&cnt[pg], pcnt);
  }
}

// ---------------- classifier + softmax ----------------

__global__ void classifier(const float* __restrict__ pooled, const float* __restrict__ cnt,
                           const float* __restrict__ Wc, const float* __restrict__ bc,
                           float* __restrict__ out, int B) {
  int g = blockIdx.x * blockDim.x + threadIdx.x;
  if (g >= B) return;
  float c = fmaxf(cnt[g], 1.f);
  float lg[NCLS];
#pragma unroll
  for (int cc = 0; cc < NCLS; ++cc) lg[cc] = bc[cc];
  for (int k = 0; k < HID; ++k) {
    float hg = pooled[(size_t)g * HID + k] / c;
#pragma unroll
    for (int cc = 0; cc < NCLS; ++cc) lg[cc] = fmaf(hg, Wc[k * NCLS + cc], lg[cc]);
  }
  float m = lg[0];
#pragma unroll
  for (int cc = 1; cc < NCLS; ++cc) m = fmaxf(m, lg[cc]);
  float s = 0.f;
#pragma unroll
  for (int cc = 0; cc < NCLS; ++cc) { lg[cc] = __expf(lg[cc] - m); s += lg[cc]; }
  float inv = 1.f / s;
#pragma unroll
  for (int cc = 0; cc < NCLS; ++cc) out[(size_t)g * NCLS + cc] = lg[cc] * inv;
}

// ---------------- launch ----------------

extern "C" void kernel_launch(void* const* d_in, const int* in_sizes, int n_in,
                              void* d_out, int out_size, void* d_ws, size_t ws_size,
                              hipStream_t stream) {
  const float* h   = (const float*)d_in[0];
  const int* src   = (const int*)d_in[1];
  const int* dst   = (const int*)d_in[2];
  const int* rel   = (const int*)d_in[3];
  const int* n2g   = (const int*)d_in[4];
  const float* W1  = (const float*)d_in[5];
  const float* Wl1 = (const float*)d_in[6];
  const float* b1  = (const float*)d_in[7];
  const float* W2  = (const float*)d_in[8];
  const float* Wl2 = (const float*)d_in[9];
  const float* b2  = (const float*)d_in[10];
  const float* Wc  = (const float*)d_in[11];
  const float* bc  = (const float*)d_in[12];

  const int N = in_sizes[0] / IN_DIM;
  const int E = in_sizes[1];
  const int B = out_size / NCLS;

  const int maxchunks = (E + 63) / 64 + NREL;   // every bucket padded to 64
  const int Epad = maxchunks * 64;

  // workspace layout (all 4-byte elements); agg has N+1 rows (row N = pad sink)
  float* agg    = (float*)d_ws;                       // (N+1)*HID
  float* h1     = agg + (size_t)(N + 1) * HID;        // N*HID
  int*   ssrc   = (int*)(h1 + (size_t)N * HID);       // Epad
  int*   sdst   = ssrc + Epad;                        // Epad
  int*   hist   = sdst + Epad;                        // 16
  int*   offs   = hist + NREL;                        // 17
  int*   fill   = offs + NREL + 1;                    // 16
  float* pooled = (float*)(fill + NREL);              // B*HID
  float* cnt    = pooled + (size_t)B * HID;           // B

  hipMemsetAsync(hist, 0, NREL * sizeof(int), stream);
  hipMemsetAsync(pooled, 0, (size_t)(B * HID + B) * sizeof(float), stream);

  fill_pad<<<(Epad + 255) / 256, 256, 0, stream>>>(ssrc, sdst, Epad, N);
  hist_rel<<<1024, 256, 0, stream>>>(rel, hist, E);
  scan16<<<1, 64, 0, stream>>>(hist, offs, fill);
  scatter_rel<<<(E + 255) / 256, 256, 0, stream>>>(rel, src, dst, fill, ssrc, sdst, E);

  const int eblocks = (maxchunks + 3) / 4;   // 4 waves per 256-thread block

  hipMemsetAsync(agg, 0, (size_t)(N + 1) * HID * sizeof(float), stream);
  edge_layer<IN_DIM><<<eblocks, 256, 0, stream>>>(h, ssrc, sdst, W1, offs, agg, maxchunks);
  finalize1<<<2048, 256, 0, stream>>>(agg, h, Wl1, b1, h1, N);

  hipMemsetAsync(agg, 0, (size_t)(N + 1) * HID * sizeof(float), stream);
  edge_layer<HID><<<eblocks, 256, 0, stream>>>(h1, ssrc, sdst, W2, offs, agg, maxchunks);
  finalize2_pool<<<2048, 256, 0, stream>>>(agg, h1, Wl2, b2, n2g, pooled, cnt, N);

  classifier<<<(B + 127) / 128, 128, 0, stream>>>(pooled, cnt, Wc, bc, (float*)d_out, B);
}